// Round 5
// baseline (523.835 us; speedup 1.0000x reference)
//
#include <hip/hip_runtime.h>
#include <hip/hip_bf16.h>

#define IN_F 4096
#define OUT_F 4096
#define M_ROWS 8192          // 4 * 2048
#define GROUP 128

#define BM 128
#define BN 128
#define KT_TILES (IN_F / 32)   // 128 k-tiles (32-k each) per row-tile

// Tiled workspace layout ("fragment order"), unchanged from round 4:
//   element [row][k] -> block ((row>>4)*KT_TILES + (k>>5)) of 512 shorts;
//   inner offset = (((k>>3)&3)*16 + (row&15))*8 + (k&7)
// global_load_lds of one block stages 1024 contiguous bytes that land in LDS
// already in MFMA A/B fragment order (lane l = A[row=l&15][k=(l>>4)*8+j]).

typedef __attribute__((ext_vector_type(8))) short short8;
typedef __attribute__((ext_vector_type(4))) float floatx4;

__device__ __forceinline__ unsigned short f2bf(float f) {
    unsigned int u = __builtin_bit_cast(unsigned int, f);
    u += 0x7fffu + ((u >> 16) & 1u);   // RNE
    return (unsigned short)(u >> 16);
}

__device__ __forceinline__ void load_lds16(const unsigned short* g, unsigned short* l) {
    __builtin_amdgcn_global_load_lds(
        (const __attribute__((address_space(1))) void*)g,
        (__attribute__((address_space(3))) void*)l,
        16, 0, 0);
}

// ---------------------------------------------------------------------------
// Kernel 1: x fp32 -> xb_t bf16 tiled. Block: 16 rows x 256 k. (round 4)
// ---------------------------------------------------------------------------
__global__ __launch_bounds__(256) void convert_x_kernel(const float* __restrict__ x,
                                                        unsigned short* __restrict__ xb) {
    __shared__ unsigned short tile[16 * 256];   // 8 KB, output (tiled) order

    const int t  = threadIdx.x;
    const int m0 = blockIdx.y * 16;
    const int k0 = blockIdx.x * 256;

    {
        const int r = t & 15;
        const int c = t >> 4;                  // 0..15, 16 floats each
        const float4* src = (const float4*)(x + (size_t)(m0 + r) * IN_F + k0 + c * 16);
        float4 f[4];
#pragma unroll
        for (int i = 0; i < 4; ++i) f[i] = src[i];
        const float* fs = (const float*)f;
#pragma unroll
        for (int h = 0; h < 2; ++h) {
            const int kl = c * 16 + h * 8;
            const int kt_l = kl >> 5;
            const int q    = (kl >> 3) & 3;
            union { unsigned short us[8]; uint4 v; } o;
#pragma unroll
            for (int j = 0; j < 8; ++j) o.us[j] = f2bf(fs[h * 8 + j]);
            *(uint4*)&tile[kt_l * 512 + (q * 16 + r) * 8] = o.v;
        }
    }

    __syncthreads();

    {
        unsigned short* dst = xb + ((size_t)blockIdx.y * KT_TILES + blockIdx.x * 8) * 512;
        *(uint4*)&dst[t * 8]        = *(const uint4*)&tile[t * 8];
        *(uint4*)&dst[2048 + t * 8] = *(const uint4*)&tile[2048 + t * 8];
    }
}

// ---------------------------------------------------------------------------
// Kernel 2: dequant -> wt_t bf16 tiled. Block: 64 n x 32 kp. (round 4)
// ---------------------------------------------------------------------------
#define DQ_KP 32
#define DQ_N  64

__global__ __launch_bounds__(256) void dequant_kernel(const int* __restrict__ qw,
                                                      const int* __restrict__ qz,
                                                      const float* __restrict__ sc,
                                                      unsigned short* __restrict__ wt) {
    __shared__ unsigned short tile[4 * 8 * 512];   // 32 KB: [tn_l][kt_l][512]

    const int t   = threadIdx.x;
    const int kp0 = blockIdx.x * DQ_KP;
    const int n0  = blockIdx.y * DQ_N;

    {
        const int kp_l = t >> 3;            // 0..31
        const int nq   = t & 7;             // 8-n chunk
        const int kp   = kp0 + kp_l;
        const int g    = kp >> 4;
        const int nb   = n0 + nq * 8;

        const uint4 q0 = *(const uint4*)&qw[(size_t)kp * OUT_F + nb];
        const uint4 q1 = *(const uint4*)&qw[(size_t)kp * OUT_F + nb + 4];
        const unsigned zq = (unsigned)qz[g * (OUT_F / 8) + (nb >> 3)];
        const float4 s0 = *(const float4*)&sc[(size_t)g * OUT_F + nb];
        const float4 s1 = *(const float4*)&sc[(size_t)g * OUT_F + nb + 4];

        unsigned qv[8] = {q0.x, q0.y, q0.z, q0.w, q1.x, q1.y, q1.z, q1.w};
        float    sv[8] = {s0.x, s0.y, s0.z, s0.w, s1.x, s1.y, s1.z, s1.w};

        const int kt_l  = kp_l >> 2;
        const int q_out = kp_l & 3;
        const int tn_l  = nq >> 1;

#pragma unroll
        for (int c = 0; c < 8; ++c) {
            const unsigned q = qv[c];
            const float zero = (float)(((zq >> (4 * c)) & 15u) + 1u);
            const float s = sv[c];
            const int r = (nq * 8 + c) & 15;
            union { unsigned short us[8]; uint4 v; } o;
#pragma unroll
            for (int j = 0; j < 8; ++j) {
                const float w = (float)((q >> (4 * j)) & 15u);
                o.us[j] = f2bf(s * (w - zero));
            }
            *(uint4*)&tile[(tn_l * 8 + kt_l) * 512 + (q_out * 16 + r) * 8] = o.v;
        }
    }

    __syncthreads();

    {
        const int tn0 = blockIdx.y * 4;
        const int kt0 = blockIdx.x * 8;
#pragma unroll
        for (int tn_l = 0; tn_l < 4; ++tn_l) {
            unsigned short* dst = wt + ((size_t)(tn0 + tn_l) * KT_TILES + kt0) * 512;
            const unsigned short* srcl = &tile[tn_l * 4096];
            *(uint4*)&dst[t * 8]        = *(const uint4*)&srcl[t * 8];
            *(uint4*)&dst[2048 + t * 8] = *(const uint4*)&srcl[2048 + t * 8];
        }
    }
}

// ---------------------------------------------------------------------------
// Kernel 3: bf16 MFMA GEMM, 128x128 tile, BK=64 (2 k-tiles per barrier).
// LDS: As/Bs = [ktl][rt][512] fragment-ordered, 16 KB each (32 KB total).
// Per iteration: 8 global_load_lds (1 KB contiguous each), 2 fragment
// rounds x 16 MFMAs -> half the barrier drains of round 4.
// ---------------------------------------------------------------------------
__global__ __launch_bounds__(256) void gemm_kernel(const unsigned short* __restrict__ xb,
                                                   const unsigned short* __restrict__ wt,
                                                   const float* __restrict__ bias,
                                                   float* __restrict__ out) {
    __shared__ unsigned short As[2 * 8 * 512];   // 16 KB
    __shared__ unsigned short Bs[2 * 8 * 512];   // 16 KB

    const int tid  = threadIdx.x;
    const int wid  = tid >> 6;
    const int lane = tid & 63;
    const int TM0 = blockIdx.y * 8;          // first m-tile (16 rows each)
    const int TN0 = blockIdx.x * 8;
    const int wave_m = wid & 1;
    const int wave_n = wid >> 1;

    floatx4 acc[4][4] = {};

    // per-lane staging sources (contiguous 1024 B per k-tile chunk)
    const unsigned short* ga0 = xb + ((size_t)(TM0 + wid + 0) * KT_TILES) * 512 + lane * 8;
    const unsigned short* ga1 = xb + ((size_t)(TM0 + wid + 4) * KT_TILES) * 512 + lane * 8;
    const unsigned short* gb0 = wt + ((size_t)(TN0 + wid + 0) * KT_TILES) * 512 + lane * 8;
    const unsigned short* gb1 = wt + ((size_t)(TN0 + wid + 4) * KT_TILES) * 512 + lane * 8;

    unsigned short* la00 = &As[(0 * 8 + wid + 0) * 512];
    unsigned short* la01 = &As[(0 * 8 + wid + 4) * 512];
    unsigned short* la10 = &As[(1 * 8 + wid + 0) * 512];
    unsigned short* la11 = &As[(1 * 8 + wid + 4) * 512];
    unsigned short* lb00 = &Bs[(0 * 8 + wid + 0) * 512];
    unsigned short* lb01 = &Bs[(0 * 8 + wid + 4) * 512];
    unsigned short* lb10 = &Bs[(1 * 8 + wid + 0) * 512];
    unsigned short* lb11 = &Bs[(1 * 8 + wid + 4) * 512];

    const int a_base = wave_m * 4 * 512 + lane * 8;
    const int b_base = wave_n * 4 * 512 + lane * 8;

    for (int kt = 0; kt < KT_TILES; kt += 2) {
        __syncthreads();
        load_lds16(ga0 + (size_t)(kt + 0) * 512, la00);
        load_lds16(ga1 + (size_t)(kt + 0) * 512, la01);
        load_lds16(ga0 + (size_t)(kt + 1) * 512, la10);
        load_lds16(ga1 + (size_t)(kt + 1) * 512, la11);
        load_lds16(gb0 + (size_t)(kt + 0) * 512, lb00);
        load_lds16(gb1 + (size_t)(kt + 0) * 512, lb01);
        load_lds16(gb0 + (size_t)(kt + 1) * 512, lb10);
        load_lds16(gb1 + (size_t)(kt + 1) * 512, lb11);
        __syncthreads();

#pragma unroll
        for (int ktl = 0; ktl < 2; ++ktl) {
            short8 a[4], b[4];
#pragma unroll
            for (int i = 0; i < 4; ++i)
                a[i] = *(const short8*)&As[ktl * 8 * 512 + a_base + i * 512];
#pragma unroll
            for (int j = 0; j < 4; ++j)
                b[j] = *(const short8*)&Bs[ktl * 8 * 512 + b_base + j * 512];
#pragma unroll
            for (int i = 0; i < 4; ++i)
#pragma unroll
                for (int j = 0; j < 4; ++j)
                    acc[i][j] = __builtin_amdgcn_mfma_f32_16x16x32_bf16(a[i], b[j], acc[i][j], 0, 0, 0);
        }
    }

    // epilogue: C/D layout col = lane&15, row = (lane>>4)*4 + reg
    const int mrow = TM0 * 16 + wave_m * 64 + (lane >> 4) * 4;
    const int ncol = TN0 * 16 + wave_n * 64 + (lane & 15);
#pragma unroll
    for (int j = 0; j < 4; ++j) {
        const int n = ncol + j * 16;
        const float bv = bias[n];
#pragma unroll
        for (int i = 0; i < 4; ++i) {
            const int m = mrow + i * 16;
#pragma unroll
            for (int r = 0; r < 4; ++r)
                out[(size_t)(m + r) * OUT_F + n] = acc[i][j][r] + bv;
        }
    }
}

extern "C" void kernel_launch(void* const* d_in, const int* in_sizes, int n_in,
                              void* d_out, int out_size, void* d_ws, size_t ws_size,
                              hipStream_t stream) {
    const float* x    = (const float*)d_in[0];
    const int*   qw   = (const int*)d_in[1];
    const int*   qz   = (const int*)d_in[2];
    const float* sc   = (const float*)d_in[3];
    const float* bias = (const float*)d_in[4];
    float* out = (float*)d_out;

    unsigned short* xb = (unsigned short*)d_ws;                       // 64 MiB tiled
    unsigned short* wt = xb + (size_t)M_ROWS * IN_F;                  // +32 MiB tiled

    convert_x_kernel<<<dim3(IN_F / 256, M_ROWS / 16), 256, 0, stream>>>(x, xb);
    dequant_kernel<<<dim3(IN_F / 8 / DQ_KP, OUT_F / DQ_N), 256, 0, stream>>>(qw, qz, sc, wt);
    gemm_kernel<<<dim3(OUT_F / BN, M_ROWS / BM), 256, 0, stream>>>(xb, wt, bias, out);
}